// Round 7
// baseline (205.367 us; speedup 1.0000x reference)
//
#include <hip/hip_runtime.h>
#include <cmath>

// MenuLoss, round 7: occupancy + per-point-cost tuning of the LDS-table kernel.
//  - theta table M=4096 (16KB LDS, quad-interp err ~1.4e-3/pt RMS, ~70x under
//    threshold via iid-coeff RMS model) -> ~17KB total LDS -> 8 blocks/CU
//  - /111 exact division -> fmaf(x, 1/111, -1) + upper clamp (acos(1+eps)=NaN
//    guard); saves the ~10-instr exact-div sequence per true point
//  - finalize merged into loss_main via device-scope atomic counter
//    (last block reduces 3584 partials; counter self-resets for graph replay)

constexpr int NCOEF = 447;
constexpr int NTAB  = 223;
constexpr int MQ    = 4096;                  // theta intervals; MQ+1 nodes
constexpr float SCALEQ = (float)(4096.0 / 3.14159265358979323846);
constexpr float HQ     = (float)(3.14159265358979323846 / 4096.0);
constexpr float INV111 = 1.0f / 111.0f;
constexpr int TPB = 256;
constexpr int NBLK = 3584;                   // 7 blocks/batch, 1024 pairs each

__device__ float g_tabF[MQ + 1];             // f(theta_j), 16KB
__device__ float g_pred[NTAB];               // exact table at integer ids
__device__ float4 g_part[NBLK];              // per-block partials (pen, ct, cp, _)
__device__ int   g_done;                     // .bss zero-init; self-resetting

__device__ __forceinline__ float tanh4(float v) {
  // v >= 0 here. tanh(4v) = 1 - 2/(exp(8v)+1); exp(large)->inf->rcp->0->1.
  float e = __expf(8.0f * v);
  return fmaf(-2.0f, __builtin_amdgcn_rcpf(e + 1.0f), 1.0f);
}

// One thread per table node (4097 theta nodes + 223 pred-integer nodes).
__global__ __launch_bounds__(256)
void build_tables(const float* __restrict__ coeffs)
{
  int g = blockIdx.x * 256 + threadIdx.x;
  float x;
  if (g <= MQ) {
    x = cosf((float)g * HQ);                 // node value x_j = cos(j*h)
  } else if (g < MQ + 1 + NTAB) {
    float kf = (float)(g - (MQ + 1));
    float m = kf / (1.0f + __expf(50.0f * (kf - 222.5f)));  // reference _mask
    x = m / 111.0f - 1.0f;                   // exact div matches reference
  } else {
    return;
  }
  float x2 = x + x;
  float Ta = 1.0f, Tb = x;
  float acc = fmaf(coeffs[1], x, coeffs[0]);
  for (int i = 2; i + 1 < NCOEF; i += 2) {   // zero-move pairwise recurrence
    Ta = fmaf(x2, Tb, -Ta); acc = fmaf(coeffs[i],     Ta, acc);
    Tb = fmaf(x2, Ta, -Tb); acc = fmaf(coeffs[i + 1], Tb, acc);
  }
  Ta = fmaf(x2, Tb, -Ta); acc = fmaf(coeffs[NCOEF - 1], Ta, acc);  // i = 446

  if (g <= MQ) g_tabF[g] = acc;
  else         g_pred[g - (MQ + 1)] = acc;
}

__device__ __forceinline__ float true_cal(const float* sf, float id) {
  float xn = fminf(fmaf(id, INV111, -1.0f), 1.0f);  // clamp: acos(1+eps)=NaN
  float th = acosf(xn) * SCALEQ;             // in [0, MQ]
  float ir = rintf(th);
  ir = ir < 1.0f ? 1.0f : (ir > (float)(MQ - 1) ? (float)(MQ - 1) : ir);
  int i = (int)ir;
  float d = th - ir;                         // in [-0.5, 0.5]
  float fm = sf[i - 1], f0 = sf[i], fp = sf[i + 1];
  float ca = 0.5f * (fp - fm);
  float cb = fmaf(0.5f, fp + fm, -f0);       // (fp - 2 f0 + fm)/2
  return fmaf(d, fmaf(d, cb, ca), f0);
}

// grid 3584: blockIdx.x = batch*7 + slice; 1024 pairs (512 float4) per block.
__global__ __launch_bounds__(TPB, 8)
void loss_main(const float4* __restrict__ yp4, const float4* __restrict__ yt4,
               float* __restrict__ out)
{
  __shared__ __align__(16) float sf[MQ + 1]; // 16KB theta table
  __shared__ float spred[NTAB];
  __shared__ float sred[12];
  const int tid = threadIdx.x;

  // cooperative LDS fill: 1024 float4 + tail (L2-hot lines)
  const float4* gt4 = (const float4*)g_tabF;
  #pragma unroll
  for (int k = 0; k < 4; ++k) ((float4*)sf)[tid + k * TPB] = gt4[tid + k * TPB];
  if (tid == 0) sf[MQ] = g_tabF[MQ];
  if (tid < NTAB) spred[tid] = g_pred[tid];
  __syncthreads();

  const size_t base = (size_t)blockIdx.x * 512;

  float pen = 0.0f, cp = 0.0f, ct = 0.0f;

  #pragma unroll
  for (int k = 0; k < 2; ++k) {
    float4 pv = yp4[base + tid + k * TPB];
    float4 tv = yt4[base + tid + k * TPB];

    // ---- pred side: penalties + exact integer-table lookup ----
    float a0 = tanh4(pv.x), b0 = tanh4(pv.y);
    pen += fmaf(b0, fmaf(-2.0f, a0, 1.0f), a0) + fmaxf(pv.x - 222.0f, 0.0f);
    int x0 = (int)rintf(pv.x); x0 = x0 < 0 ? 0 : (x0 > NTAB - 1 ? NTAB - 1 : x0);
    cp = fmaf(spred[x0], pv.y, cp);
    float a1 = tanh4(pv.z), b1 = tanh4(pv.w);
    pen += fmaf(b1, fmaf(-2.0f, a1, 1.0f), a1) + fmaxf(pv.z - 222.0f, 0.0f);
    int x1 = (int)rintf(pv.z); x1 = x1 < 0 ? 0 : (x1 > NTAB - 1 ? NTAB - 1 : x1);
    cp = fmaf(spred[x1], pv.w, cp);

    // ---- true side: quadratic interp on LDS theta table ----
    ct = fmaf(true_cal(sf, tv.x), tv.y, ct);
    ct = fmaf(true_cal(sf, tv.z), tv.w, ct);
  }

  #pragma unroll
  for (int o = 32; o > 0; o >>= 1) {
    pen += __shfl_down(pen, o, 64);
    ct  += __shfl_down(ct,  o, 64);
    cp  += __shfl_down(cp,  o, 64);
  }
  const int w = tid >> 6;
  if ((tid & 63) == 0) { sred[w] = pen; sred[4 + w] = ct; sred[8 + w] = cp; }
  __syncthreads();

  __shared__ bool s_last;
  if (tid == 0) {
    g_part[blockIdx.x] =
        make_float4(sred[0] + sred[1] + sred[2]  + sred[3],
                    sred[4] + sred[5] + sred[6]  + sred[7],
                    sred[8] + sred[9] + sred[10] + sred[11], 0.0f);
    __threadfence();                          // partial visible before count
    s_last = (atomicAdd(&g_done, 1) == NBLK - 1);
  }
  __syncthreads();
  if (!s_last) return;

  // ---- last block: finalize (2 batches/thread, 7 slices each) ----
  __threadfence();                            // acquire all partials
  float acc = 0.0f;
  #pragma unroll
  for (int r = 0; r < 2; ++r) {
    int b = 2 * tid + r;                      // batch index
    float p = 0.0f, tsum = 0.0f, psum = 0.0f;
    #pragma unroll
    for (int s = 0; s < 7; ++s) {
      float4 u = g_part[b * 7 + s];
      p += u.x; tsum += u.y; psum += u.z;
    }
    float d = (tsum - psum) * (1.0f / 700.0f);
    acc += fmaf(d, d, p);
  }
  #pragma unroll
  for (int o = 32; o > 0; o >>= 1) acc += __shfl_down(acc, o, 64);
  if ((tid & 63) == 0) sred[tid >> 6] = acc;
  __syncthreads();
  if (tid == 0) {
    out[0] = (sred[0] + sred[1] + sred[2] + sred[3]) * (1.0f / 512.0f);
    g_done = 0;                               // self-reset for next graph replay
  }
}

extern "C" void kernel_launch(void* const* d_in, const int* in_sizes, int n_in,
                              void* d_out, int out_size, void* d_ws, size_t ws_size,
                              hipStream_t stream) {
  build_tables<<<17, 256, 0, stream>>>((const float*)d_in[2]);
  loss_main<<<NBLK, TPB, 0, stream>>>(
      (const float4*)d_in[0], (const float4*)d_in[1], (float*)d_out);
}

// Round 8
// 104.263 us; speedup vs baseline: 1.9697x; 1.9697x over previous
//
#include <hip/hip_runtime.h>
#include <cmath>

// MenuLoss, round 8: R6 structure (best known) + two isolated deltas.
//  - theta table M=4096 (16KB LDS): halves per-block fill traffic/latency vs
//    R6's 32KB. Quad-interp err ~1.4e-3/pt RMS -> ~70x under threshold.
//  - /111 exact div -> fmaf(id, 1/111, -1) with upper clamp (acos NaN guard).
//  - NO device-scope fences / atomics (R7's merged finalize caused a 2x
//    regression: per-block __threadfence on non-coherent L2 stalled all waves).
// Structure: build_tables (17 blk) -> loss_main (1024 blk, 7 f4/thread)
//            -> finalize (1 blk).

constexpr int NCOEF = 447;
constexpr int NTAB  = 223;
constexpr int MQ    = 4096;                  // theta intervals; MQ+1 nodes
constexpr float SCALEQ = (float)(4096.0 / 3.14159265358979323846);
constexpr float HQ     = (float)(3.14159265358979323846 / 4096.0);
constexpr float INV111 = 1.0f / 111.0f;
constexpr int TPB = 256;

__device__ float g_tabF[MQ + 1];             // f(theta_j), 16KB + 4B
__device__ float g_pred[NTAB];               // exact table at integer ids
__device__ float4 g_part[1024];              // per-block partials (pen, ct, cp, _)

__device__ __forceinline__ float tanh4(float v) {
  // v >= 0 here. tanh(4v) = 1 - 2/(exp(8v)+1); exp(large)->inf->rcp->0->1.
  float e = __expf(8.0f * v);
  return fmaf(-2.0f, __builtin_amdgcn_rcpf(e + 1.0f), 1.0f);
}

// One thread per table node (4097 theta nodes + 223 pred-integer nodes).
__global__ __launch_bounds__(256)
void build_tables(const float* __restrict__ coeffs)
{
  int g = blockIdx.x * 256 + threadIdx.x;
  float x;
  if (g <= MQ) {
    x = cosf((float)g * HQ);                 // node value x_j = cos(j*h)
  } else if (g < MQ + 1 + NTAB) {
    float kf = (float)(g - (MQ + 1));
    float m = kf / (1.0f + __expf(50.0f * (kf - 222.5f)));  // reference _mask
    x = m / 111.0f - 1.0f;                   // exact div matches reference
  } else {
    return;
  }
  float x2 = x + x;
  float Ta = 1.0f, Tb = x;
  float acc = fmaf(coeffs[1], x, coeffs[0]);
  for (int i = 2; i + 1 < NCOEF; i += 2) {   // zero-move pairwise recurrence
    Ta = fmaf(x2, Tb, -Ta); acc = fmaf(coeffs[i],     Ta, acc);
    Tb = fmaf(x2, Ta, -Tb); acc = fmaf(coeffs[i + 1], Tb, acc);
  }
  Ta = fmaf(x2, Tb, -Ta); acc = fmaf(coeffs[NCOEF - 1], Ta, acc);  // i = 446

  if (g <= MQ) g_tabF[g] = acc;
  else         g_pred[g - (MQ + 1)] = acc;
}

__device__ __forceinline__ float true_cal(const float* sf, float id) {
  float xn = fminf(fmaf(id, INV111, -1.0f), 1.0f);  // clamp: acos(1+eps)=NaN
  float th = acosf(xn) * SCALEQ;             // in [0, MQ]
  float ir = rintf(th);
  ir = ir < 1.0f ? 1.0f : (ir > (float)(MQ - 1) ? (float)(MQ - 1) : ir);
  int i = (int)ir;
  float d = th - ir;                         // in [-0.5, 0.5]
  float fm = sf[i - 1], f0 = sf[i], fp = sf[i + 1];
  float ca = 0.5f * (fp - fm);
  float cb = fmaf(0.5f, fp + fm, -f0);       // (fp - 2 f0 + fm)/2
  return fmaf(d, fmaf(d, cb, ca), f0);
}

// grid 1024: blockIdx.x = batch*2 + half; 3584 pairs (1792 float4) per block.
__global__ __launch_bounds__(TPB)
void loss_main(const float4* __restrict__ yp4, const float4* __restrict__ yt4)
{
  __shared__ __align__(16) float sf[MQ + 1]; // 16KB theta table
  __shared__ float spred[NTAB];
  __shared__ float sred[12];
  const int tid = threadIdx.x;

  // cooperative LDS fill: 1024 float4 + tail (L2-hot lines)
  const float4* gt4 = (const float4*)g_tabF;
  #pragma unroll
  for (int k = 0; k < 4; ++k) ((float4*)sf)[tid + k * TPB] = gt4[tid + k * TPB];
  if (tid == 0) sf[MQ] = g_tabF[MQ];
  if (tid < NTAB) spred[tid] = g_pred[tid];
  __syncthreads();

  const int b = blockIdx.x >> 1, h = blockIdx.x & 1;
  const size_t base = (size_t)b * 3584 + (size_t)h * 1792;

  float pen = 0.0f, cp = 0.0f, ct = 0.0f;

  #pragma unroll
  for (int k = 0; k < 7; ++k) {
    float4 pv = yp4[base + tid + k * TPB];
    float4 tv = yt4[base + tid + k * TPB];

    // ---- pred side: penalties + exact integer-table lookup ----
    float a0 = tanh4(pv.x), b0 = tanh4(pv.y);
    pen += fmaf(b0, fmaf(-2.0f, a0, 1.0f), a0) + fmaxf(pv.x - 222.0f, 0.0f);
    int x0 = (int)rintf(pv.x); x0 = x0 < 0 ? 0 : (x0 > NTAB - 1 ? NTAB - 1 : x0);
    cp = fmaf(spred[x0], pv.y, cp);
    float a1 = tanh4(pv.z), b1 = tanh4(pv.w);
    pen += fmaf(b1, fmaf(-2.0f, a1, 1.0f), a1) + fmaxf(pv.z - 222.0f, 0.0f);
    int x1 = (int)rintf(pv.z); x1 = x1 < 0 ? 0 : (x1 > NTAB - 1 ? NTAB - 1 : x1);
    cp = fmaf(spred[x1], pv.w, cp);

    // ---- true side: quadratic interp on LDS theta table ----
    ct = fmaf(true_cal(sf, tv.x), tv.y, ct);
    ct = fmaf(true_cal(sf, tv.z), tv.w, ct);
  }

  #pragma unroll
  for (int o = 32; o > 0; o >>= 1) {
    pen += __shfl_down(pen, o, 64);
    ct  += __shfl_down(ct,  o, 64);
    cp  += __shfl_down(cp,  o, 64);
  }
  const int w = tid >> 6;
  if ((tid & 63) == 0) { sred[w] = pen; sred[4 + w] = ct; sred[8 + w] = cp; }
  __syncthreads();
  if (tid == 0) {
    g_part[blockIdx.x] =
        make_float4(sred[0] + sred[1] + sred[2]  + sred[3],
                    sred[4] + sred[5] + sred[6]  + sred[7],
                    sred[8] + sred[9] + sred[10] + sred[11], 0.0f);
  }
}

__global__ __launch_bounds__(512)
void finalize(float* __restrict__ out)
{
  __shared__ float sr[8];
  int t = threadIdx.x;                        // one thread per batch
  float4 u = g_part[2 * t], v = g_part[2 * t + 1];
  float pen = u.x + v.x;
  float d = ((u.y + v.y) - (u.z + v.z)) * (1.0f / 700.0f);
  float s = fmaf(d, d, pen);                  // sum(s) = sum d^2 + sum pen
  #pragma unroll
  for (int o = 32; o > 0; o >>= 1) s += __shfl_down(s, o, 64);
  if ((t & 63) == 0) sr[t >> 6] = s;
  __syncthreads();
  if (t == 0) {
    out[0] = (sr[0] + sr[1] + sr[2] + sr[3] +
              sr[4] + sr[5] + sr[6] + sr[7]) * (1.0f / 512.0f);
  }
}

extern "C" void kernel_launch(void* const* d_in, const int* in_sizes, int n_in,
                              void* d_out, int out_size, void* d_ws, size_t ws_size,
                              hipStream_t stream) {
  build_tables<<<17, 256, 0, stream>>>((const float*)d_in[2]);
  loss_main<<<1024, TPB, 0, stream>>>(
      (const float4*)d_in[0], (const float4*)d_in[1]);
  finalize<<<1, 512, 0, stream>>>((float*)d_out);
}